// Round 1
// baseline (1284.001 us; speedup 1.0000x reference)
//
#include <hip/hip_runtime.h>

using short8 = __attribute__((ext_vector_type(8))) short;
using f32x4  = __attribute__((ext_vector_type(4))) float;

__device__ __forceinline__ unsigned short f2bf(float f) {
  unsigned int u = __builtin_bit_cast(unsigned int, f);
  u += 0x7fffu + ((u >> 16) & 1u);          // RNE
  return (unsigned short)(u >> 16);
}
__device__ __forceinline__ float bf2f(unsigned short h) {
  return __builtin_bit_cast(float, ((unsigned int)h) << 16);
}

__device__ __forceinline__ void async16(const void* g, void* l) {
  __builtin_amdgcn_global_load_lds((const __attribute__((address_space(1))) unsigned int*)g,
                                   (__attribute__((address_space(3))) unsigned int*)l, 16, 0, 0);
}

// ---------------------------------------------------------------------------
// Generic B^T GEMM: C[M,N] = A[M,K] * B[N,K]^T (+bias). bf16 inputs, 128x128
// tile, 4 waves * 4x4 grid of 16x16x32 MFMA (m97 recipe). M,Npad mult of 128,
// K mult of 32. Store guarded by col < Nreal; C row stride = Nreal.
// ---------------------------------------------------------------------------
template<int OUT_BF16, int HAS_BIAS>
__global__ __launch_bounds__(256) void gemm_bt(
    const unsigned short* __restrict__ A,
    const unsigned short* __restrict__ B,
    void* __restrict__ Cvoid,
    const float* __restrict__ bias,
    int K, int Nreal)
{
  __shared__ unsigned short As[128 * 32];
  __shared__ unsigned short Bs[128 * 32];
  const int tid  = threadIdx.x;
  const int lane = tid & 63;
  const int wv   = tid >> 6;
  const int wm   = (wv >> 1) * 64;
  const int wn   = (wv & 1) * 64;
  const long m0  = (long)blockIdx.x * 128;
  const long n0  = (long)blockIdx.y * 128;

  const int rr = tid >> 2;          // staging row 0..63
  const int kk = (tid & 3) * 8;     // k offset 0,8,16,24
  const unsigned short* Ag = A + (m0 + rr) * (long)K + kk;
  const unsigned short* Bg = B + (n0 + rr) * (long)K + kk;
  unsigned short* AsD = As + tid * 8;
  unsigned short* BsD = Bs + tid * 8;

  f32x4 acc[4][4] = {};

  const int nKt = K >> 5;
  for (int kt = 0; kt < nKt; ++kt) {
    __syncthreads();                       // prior frag reads done
    const int ko = kt * 32;
    async16(Ag + ko, AsD);
    async16(Ag + 64L * K + ko, AsD + 2048);
    async16(Bg + ko, BsD);
    async16(Bg + 64L * K + ko, BsD + 2048);
    __syncthreads();                       // vmcnt(0) drain at barrier
    const int lr = lane & 15;
    const int kg = (lane >> 4) * 8;
    short8 af[4], bfr[4];
#pragma unroll
    for (int i = 0; i < 4; ++i)
      af[i] = *(const short8*)(As + (wm + i * 16 + lr) * 32 + kg);
#pragma unroll
    for (int j = 0; j < 4; ++j)
      bfr[j] = *(const short8*)(Bs + (wn + j * 16 + lr) * 32 + kg);
#pragma unroll
    for (int i = 0; i < 4; ++i)
#pragma unroll
      for (int j = 0; j < 4; ++j)
        acc[i][j] = __builtin_amdgcn_mfma_f32_16x16x32_bf16(af[i], bfr[j], acc[i][j], 0, 0, 0);
  }

  // epilogue: C/D layout col = lane&15, row = (lane>>4)*4 + reg  [m89/m91 verified]
  const int lr2 = lane & 15;
  const int lg  = (lane >> 4) * 4;
#pragma unroll
  for (int j = 0; j < 4; ++j) {
    const long col = n0 + wn + j * 16 + lr2;
    if (col >= Nreal) continue;
    const float bv = HAS_BIAS ? bias[col] : 0.f;
#pragma unroll
    for (int i = 0; i < 4; ++i) {
#pragma unroll
      for (int r = 0; r < 4; ++r) {
        const long row = m0 + wm + i * 16 + lg + r;
        const float v = acc[i][j][r] + bv;
        if (OUT_BF16) ((unsigned short*)Cvoid)[row * Nreal + col] = f2bf(v);
        else          ((float*)Cvoid)[row * Nreal + col] = v;
      }
    }
  }
}

// ---------------------------------------------------------------------------
// fuseW fp32 [100000,256] -> bf16 [100096,256] zero-padded
// ---------------------------------------------------------------------------
__global__ __launch_bounds__(256) void convert_fuseW(const float* __restrict__ fw,
                                                     unsigned short* __restrict__ out)
{
  const size_t i = ((size_t)blockIdx.x * 256 + threadIdx.x) * 8;
  short8 o;
  if (i < 25600000ULL) {
    float4 a = *(const float4*)(fw + i);
    float4 b = *(const float4*)(fw + i + 4);
    o[0] = f2bf(a.x); o[1] = f2bf(a.y); o[2] = f2bf(a.z); o[3] = f2bf(a.w);
    o[4] = f2bf(b.x); o[5] = f2bf(b.y); o[6] = f2bf(b.z); o[7] = f2bf(b.w);
  } else {
#pragma unroll
    for (int k = 0; k < 8; ++k) o[k] = 0;
  }
  *(short8*)(out + i) = o;
}

// ---------------------------------------------------------------------------
// small weights -> bf16: sp_w, tp_w, aW halves, Bcat=[W|sW|tW] (512x384)
// ---------------------------------------------------------------------------
__global__ __launch_bounds__(256) void prep_small(
    const float* __restrict__ spw, const float* __restrict__ tpw,
    const float* __restrict__ spaW, const float* __restrict__ tpaW,
    const float* __restrict__ W, const float* __restrict__ sWm, const float* __restrict__ tWm,
    unsigned short* __restrict__ o_spw, unsigned short* __restrict__ o_tpw,
    unsigned short* __restrict__ o_a1sp, unsigned short* __restrict__ o_a2sp,
    unsigned short* __restrict__ o_a1tp, unsigned short* __restrict__ o_a2tp,
    unsigned short* __restrict__ o_bcat)
{
  int i = blockIdx.x * 256 + threadIdx.x;
  if (i < 16384) { o_spw[i] = f2bf(spw[i]); return; }
  i -= 16384;
  if (i < 16384) { o_tpw[i] = f2bf(tpw[i]); return; }
  i -= 16384;
  if (i < 16384) { int f = i >> 7, c = i & 127; o_a1sp[i] = f2bf(spaW[f * 256 + c]); return; }
  i -= 16384;
  if (i < 16384) { int f = i >> 7, c = i & 127; o_a2sp[i] = f2bf(spaW[f * 256 + 128 + c]); return; }
  i -= 16384;
  if (i < 16384) { int f = i >> 7, c = i & 127; o_a1tp[i] = f2bf(tpaW[f * 256 + c]); return; }
  i -= 16384;
  if (i < 16384) { int f = i >> 7, c = i & 127; o_a2tp[i] = f2bf(tpaW[f * 256 + 128 + c]); return; }
  i -= 16384;
  const int j = i / 384, c = i - j * 384;
  const float v = (c < 128) ? W[j * 128 + c]
                : (c < 256) ? sWm[j * 128 + c - 128]
                            : tWm[j * 128 + c - 256];
  o_bcat[i] = f2bf(v);
}

// ---------------------------------------------------------------------------
// Embedding gathers -> bf16: Xcat=[sp_nb;x;tp_nb;x] (69632x128),
// A2[:,0:128]=x_emb (stride 384), Afuse[:,0:128]=u_emb (stride 256)
// ---------------------------------------------------------------------------
__global__ __launch_bounds__(256) void gather_embed(
    const int* __restrict__ x, const int* __restrict__ users,
    const int* __restrict__ spn, const int* __restrict__ tpn,
    const float* __restrict__ poi, const float* __restrict__ utab,
    unsigned short* __restrict__ Xcat, unsigned short* __restrict__ A2,
    unsigned short* __restrict__ Afuse)
{
  const unsigned int t = blockIdx.x * 256 + threadIdx.x;
  const unsigned int c = (t & 31) * 4;
  const unsigned int row = t >> 5;
  const float* src;
  unsigned short* dst;
  if (row < 69632u) {
    int sr;
    if (row < 32768u)      sr = spn[row];
    else if (row < 34816u) sr = x[row - 32768u];
    else if (row < 67584u) sr = tpn[row - 34816u];
    else                   sr = x[row - 67584u];
    src = poi + (size_t)sr * 128 + c;
    dst = Xcat + (size_t)row * 128 + c;
  } else if (row < 71680u) {
    const unsigned int m = row - 69632u;
    src = poi + (size_t)x[m] * 128 + c;
    dst = A2 + (size_t)m * 384 + c;
  } else {
    const unsigned int m = row - 71680u;
    src = utab + (size_t)users[m] * 128 + c;
    dst = Afuse + (size_t)m * 256 + c;
  }
  const float4 v = *(const float4*)src;
  ushort4 o;
  o.x = f2bf(v.x); o.y = f2bf(v.y); o.z = f2bf(v.z); o.w = f2bf(v.w);
  *(ushort4*)dst = o;
}

// ---------------------------------------------------------------------------
// GAT epilogue: e = leaky(q + r + ab), softmax over n (16), out = sum a*pn.
// Writes spatial (side 0) / temporal (side 1) bf16 into A2 cols 128/256.
// ---------------------------------------------------------------------------
__global__ __launch_bounds__(128) void gat_softmax_out(
    const float* __restrict__ Q, const float* __restrict__ R,
    const unsigned short* __restrict__ P,
    const float* __restrict__ sp_ab, const float* __restrict__ tp_ab,
    unsigned short* __restrict__ A2)
{
  const int m = blockIdx.x;
  const int side = blockIdx.y;
  const int f = threadIdx.x;
  const float* q = Q + ((size_t)side * 2048 + m) * 128;
  const float* r = R + ((size_t)side * 32768 + (size_t)m * 16) * 128;
  const unsigned short* pn = P + ((size_t)side * 34816 + (size_t)m * 16) * 128;
  const float ab = (side ? tp_ab : sp_ab)[f];
  const float qf = q[f] + ab;
  float e[16];
  float mx = -1e30f;
#pragma unroll
  for (int n = 0; n < 16; ++n) {
    float v = qf + r[n * 128 + f];
    v = (v >= 0.f) ? v : 0.01f * v;          // LeakyReLU(0.01)
    e[n] = v;
    mx = fmaxf(mx, v);
  }
  float sum = 0.f;
#pragma unroll
  for (int n = 0; n < 16; ++n) { const float ex = __expf(e[n] - mx); e[n] = ex; sum += ex; }
  float o = 0.f;
#pragma unroll
  for (int n = 0; n < 16; ++n) o += e[n] * bf2f(pn[n * 128 + f]);
  o /= sum;
  A2[(size_t)m * 384 + 128 + side * 128 + f] = f2bf(o);
}

// ---------------------------------------------------------------------------
// LSTM recurrence: one block per batch row b (independent sequences).
// 512 threads: thread j owns pre-activation j; U row in 128 VGPRs (fp32).
// h broadcast through LDS; c in registers of threads j<128. Gate order i,f,o,g.
// ---------------------------------------------------------------------------
__global__ __launch_bounds__(512) void lstm_kernel(
    const float* __restrict__ pre, const float* __restrict__ U,
    unsigned short* __restrict__ Afuse)
{
  const int b = blockIdx.x;
  const int j = threadIdx.x;
  __shared__ float h_lds[128];
  __shared__ float pre_lds[512];
  float u[128];
#pragma unroll
  for (int e = 0; e < 128; e += 4) {
    const float4 v = *(const float4*)(U + (size_t)j * 128 + e);
    u[e] = v.x; u[e + 1] = v.y; u[e + 2] = v.z; u[e + 3] = v.w;
  }
  float c = 0.f;
  if (j < 128) h_lds[j] = 0.f;
  __syncthreads();
  const float* prow = pre + (size_t)b * 64 * 512;
  unsigned short* arow = Afuse + (size_t)b * 64 * 256;
  for (int t = 0; t < 64; ++t) {
    float s = prow[t * 512 + j];
#pragma unroll
    for (int e = 0; e < 128; e += 4) {
      const float4 hv = *(const float4*)(h_lds + e);   // wave-uniform broadcast
      s += u[e] * hv.x + u[e + 1] * hv.y + u[e + 2] * hv.z + u[e + 3] * hv.w;
    }
    pre_lds[j] = s;
    __syncthreads();                  // pre ready; all h_lds reads done
    if (j < 128) {
      const float pi = pre_lds[j], pf = pre_lds[128 + j],
                  po = pre_lds[256 + j], pg = pre_lds[384 + j];
      const float ig = 1.f / (1.f + __expf(-pi));
      const float fg = 1.f / (1.f + __expf(-pf));
      const float og = 1.f / (1.f + __expf(-po));
      const float t2 = __expf(2.f * pg);
      const float g  = (t2 - 1.f) / (t2 + 1.f);
      c = fg * c + ig * g;
      const float e2 = __expf(2.f * c);
      const float th = (e2 - 1.f) / (e2 + 1.f);
      const float h  = og * th;
      h_lds[j] = h;
      arow[t * 256 + 128 + j] = f2bf(h);
    }
    __syncthreads();                  // h visible for next step
  }
}

// ---------------------------------------------------------------------------
extern "C" void kernel_launch(void* const* d_in, const int* in_sizes, int n_in,
                              void* d_out, int out_size, void* d_ws, size_t ws_size,
                              hipStream_t stream) {
  const int*   x     = (const int*)d_in[0];
  const int*   users = (const int*)d_in[1];
  const int*   spn   = (const int*)d_in[2];
  const int*   tpn   = (const int*)d_in[3];
  const float* poi   = (const float*)d_in[4];
  const float* utab  = (const float*)d_in[5];
  const float* sp_w  = (const float*)d_in[6];
  const float* sp_aW = (const float*)d_in[7];
  const float* sp_ab = (const float*)d_in[8];
  const float* tp_w  = (const float*)d_in[9];
  const float* tp_aW = (const float*)d_in[10];
  const float* tp_ab = (const float*)d_in[11];
  const float* W     = (const float*)d_in[12];
  const float* U     = (const float*)d_in[13];
  const float* Ub    = (const float*)d_in[14];
  const float* sW    = (const float*)d_in[15];
  const float* tW    = (const float*)d_in[16];
  const float* fuseW = (const float*)d_in[17];
  const float* fuseb = (const float*)d_in[18];

  char* wsp = (char*)d_ws;
  auto take = [&](size_t bytes) -> void* {
    void* p = wsp; wsp += (bytes + 255) & ~(size_t)255; return p;
  };
  unsigned short* fuseWb = (unsigned short*)take(100096ULL * 256 * 2);
  unsigned short* Xcat   = (unsigned short*)take(69632ULL * 128 * 2);
  unsigned short* P      = (unsigned short*)take(69632ULL * 128 * 2);
  float*          Rbuf   = (float*)take(65536ULL * 128 * 4);
  float*          Qbuf   = (float*)take(4096ULL * 128 * 4);
  unsigned short* A2     = (unsigned short*)take(2048ULL * 384 * 2);
  float*          preb   = (float*)take(2048ULL * 512 * 4);
  unsigned short* Afuse  = (unsigned short*)take(2048ULL * 256 * 2);
  unsigned short* spwb   = (unsigned short*)take(16384 * 2);
  unsigned short* tpwb   = (unsigned short*)take(16384 * 2);
  unsigned short* a1sp   = (unsigned short*)take(16384 * 2);
  unsigned short* a2sp   = (unsigned short*)take(16384 * 2);
  unsigned short* a1tp   = (unsigned short*)take(16384 * 2);
  unsigned short* a2tp   = (unsigned short*)take(16384 * 2);
  unsigned short* bcat   = (unsigned short*)take(512ULL * 384 * 2);

  convert_fuseW<<<12512, 256, 0, stream>>>(fuseW, fuseWb);
  prep_small<<<1152, 256, 0, stream>>>(sp_w, tp_w, sp_aW, tp_aW, W, sW, tW,
                                       spwb, tpwb, a1sp, a2sp, a1tp, a2tp, bcat);
  gather_embed<<<9216, 256, 0, stream>>>(x, users, spn, tpn, poi, utab, Xcat, A2, Afuse);

  // GAT projections: P = Xcat @ w^T  (rows: [sp_nb; x] then [tp_nb; x])
  gemm_bt<1, 0><<<dim3(272, 1), 256, 0, stream>>>(Xcat, spwb, P, nullptr, 128, 128);
  gemm_bt<1, 0><<<dim3(272, 1), 256, 0, stream>>>(Xcat + 34816ULL * 128, tpwb,
                                                  P + 34816ULL * 128, nullptr, 128, 128);
  // attention neighbour term r = pn @ aW2^T (fp32 out)
  gemm_bt<0, 0><<<dim3(256, 1), 256, 0, stream>>>(P, a2sp, Rbuf, nullptr, 128, 128);
  gemm_bt<0, 0><<<dim3(256, 1), 256, 0, stream>>>(P + 34816ULL * 128, a2tp,
                                                  Rbuf + 32768ULL * 128, nullptr, 128, 128);
  // attention centre term q = px @ aW1^T
  gemm_bt<0, 0><<<dim3(16, 1), 256, 0, stream>>>(P + 32768ULL * 128, a1sp, Qbuf, nullptr, 128, 128);
  gemm_bt<0, 0><<<dim3(16, 1), 256, 0, stream>>>(P + 67584ULL * 128, a1tp,
                                                 Qbuf + 2048ULL * 128, nullptr, 128, 128);
  gat_softmax_out<<<dim3(2048, 2), 128, 0, stream>>>(Qbuf, Rbuf, P, sp_ab, tp_ab, A2);

  // batched LSTM pre-activations: pre = [x|s|t] @ [W|sW|tW]^T + Ub
  gemm_bt<0, 1><<<dim3(16, 4), 256, 0, stream>>>(A2, bcat, preb, Ub, 384, 512);
  lstm_kernel<<<32, 512, 0, stream>>>(preb, U, Afuse);

  // fuse head: logits = [u_emb|h] @ fuseW^T + fuseb
  gemm_bt<0, 1><<<dim3(16, 782), 256, 0, stream>>>(Afuse, fuseWb, (float*)d_out,
                                                   fuseb, 256, 100000);
}